// Round 3
// baseline (430.424 us; speedup 1.0000x reference)
//
#include <hip/hip_runtime.h>

// 2D db2 LL band: out[jh,jw] = sum_{a,b} g[a]*g[b]*x[symH(2jh-2+a), symW(2jw-2+b)]
// g = DEC_LO reversed. H=W=512 -> OH=OW=257. N*C = 256 planes.
// Memory-bound: floor = 256 MB read + 67.6 MB write ≈ 49 µs @ 6.6 TB/s.
// R2 lesson: leaving edge-tile LDS uninitialized broke graph-replay
// determinism -> zero-fill the unstaged remainder (LDS-only cost), keep the
// global-read savings (~90 MB of unused halo in the 25% edge blocks).

#define IN_H 512
#define IN_W 512
#define OUT_H 257
#define OUT_W 257

// Output tile per block
#define TW 64
#define TH 16
// Input patch needed: 2*T + 2
#define IW_T (2 * TW + 2)     // 130
#define IH_T (2 * TH + 2)     // 34
#define LDS_STRIDE (IW_T + 2) // 132, keeps float2 alignment (even)

__global__ __launch_bounds__(256, 2)
void dwt_ll_kernel(const float* __restrict__ x, float* __restrict__ out) {
    __shared__ float tile[IH_T][LDS_STRIDE];

    const int tid = threadIdx.x;
    const int jw0 = blockIdx.x * TW;
    const int jh0 = blockIdx.y * TH;
    const int plane = blockIdx.z;

    const float* __restrict__ xp = x + (size_t)plane * (IN_H * IN_W);
    float* __restrict__ op = out + (size_t)plane * (OUT_H * OUT_W);

    const int rbase = 2 * jh0 - 2;
    const int cbase = 2 * jw0 - 2;

    // Only stage what this tile's valid outputs need (OUT_W/H = 257 prime ->
    // edge tiles produce 1 row/col). Remainder is zero-filled so every LDS
    // element is defined (deterministic across graph replays).
    const int needW = min(IW_T, 2 * (OUT_W - jw0) + 2);
    const int needH = min(IH_T, 2 * (OUT_H - jh0) + 2);

    // ---- Stage input patch (symmetric boundary remap) into LDS ----
    // Loop bound & divisor are compile-time constants (fast div by 130).
    for (int idx = tid; idx < IH_T * IW_T; idx += 256) {
        const int r = idx / IW_T;
        const int c = idx - r * IW_T;
        float v = 0.0f;
        if (r < needH && c < needW) {
            int gr = rbase + r;
            int gc = cbase + c;
            gr = (gr < 0) ? (-gr - 1) : gr;
            gr = (gr >= IN_H) ? (2 * IN_H - 1 - gr) : gr;
            gc = (gc < 0) ? (-gc - 1) : gc;
            gc = (gc >= IN_W) ? (2 * IN_W - 1 - gc) : gc;
            v = xp[gr * IN_W + gc];
        }
        tile[r][c] = v;
    }
    __syncthreads();

    // db2 dec_lo reversed
    const float g0 = 0.48296291314469025f;
    const float g1 = 0.8365163037378079f;
    const float g2 = 0.22414386804185735f;
    const float g3 = -0.12940952255092145f;

    const int tx = tid & 63;   // output col within tile
    const int ty = tid >> 6;   // 0..3, handles 4 output rows each
    const int ow = jw0 + tx;
    if (ow >= OUT_W) return;   // no later barriers, safe
    // Surviving threads read LDS cols 2tx..2tx+3 <= needW-1 (staged); rows
    // beyond needH contribute only to outputs discarded by the oh guard and
    // are defined (zero) anyway.

    const int cc = 2 * tx;     // LDS col base (even -> 8B aligned)
    const int r0 = 8 * ty;     // LDS row base for this thread's 10 rows

    // Horizontal low-pass on the 10 input rows this thread's 4 outputs need
    float h[10];
#pragma unroll
    for (int r = 0; r < 10; ++r) {
        const float2 a = *(const float2*)&tile[r0 + r][cc];
        const float2 b = *(const float2*)&tile[r0 + r][cc + 2];
        h[r] = g0 * a.x + g1 * a.y + g2 * b.x + g3 * b.y;
    }

    // Vertical low-pass -> 4 outputs
#pragma unroll
    for (int k = 0; k < 4; ++k) {
        const int oh = jh0 + ty * 4 + k;
        if (oh < OUT_H) {
            const float v = g0 * h[2 * k] + g1 * h[2 * k + 1]
                          + g2 * h[2 * k + 2] + g3 * h[2 * k + 3];
            op[oh * OUT_W + ow] = v;
        }
    }
}

extern "C" void kernel_launch(void* const* d_in, const int* in_sizes, int n_in,
                              void* d_out, int out_size, void* d_ws, size_t ws_size,
                              hipStream_t stream) {
    const float* x = (const float*)d_in[0];
    float* out = (float*)d_out;

    // (4,64,512,512) -> planes = 256; output tiles: ceil(257/64)=5, ceil(257/16)=17
    dim3 grid((OUT_W + TW - 1) / TW, (OUT_H + TH - 1) / TH, 4 * 64);
    dim3 block(256);
    dwt_ll_kernel<<<grid, block, 0, stream>>>(x, out);
}

// Round 4
// 370.787 us; speedup vs baseline: 1.1608x; 1.1608x over previous
//
#include <hip/hip_runtime.h>

// 2D db2 LL band: out[oh,ow] = sum_{a,b} g[a]g[b] x[sym(2oh-2+a), sym(2ow-2+b)]
// g = DEC_LO reversed. 512x512 -> 257x257, 256 planes. Memory-bound,
// floor ~= (256 MB read + 67.6 MB write) / 6.3 TB/s ~= 51 us.
//
// R4 structure: full-width slabs. Block = 8 output rows x 257 cols of one
// plane. Staging = 18 full input rows as aligned float4 (9/thread, coalesced)
// + 6 symmetric edge cols fixed up by 144 threads. Row-reflect applied per
// row, not per element. All read LDS is written (cols 0,1 zeroed) ->
// deterministic across graph replays (R2 lesson).

#define IN_H 512
#define IN_W 512
#define OUT_H 257
#define OUT_W 257
#define TH 8
#define NROWS (2 * TH + 2)   // 18 input rows per slab
#define TSTRIDE 520          // tile col c holds input col gc = c - 4; c in [0,520)

__global__ __launch_bounds__(256, 4)
void dwt_ll_kernel(const float* __restrict__ x, float* __restrict__ out) {
    __shared__ __align__(16) float tile[NROWS][TSTRIDE];  // 37,440 B -> 4 blocks/CU

    const int tid = threadIdx.x;
    const int by = blockIdx.x;      // output row tile (0..32)
    const int plane = blockIdx.y;   // 0..255

    const float* __restrict__ xp = x + (size_t)plane * (IN_H * IN_W);
    float* __restrict__ op = out + (size_t)plane * (OUT_H * OUT_W);

    const int rbase = 2 * (TH * by) - 2;   // first input row of slab (may be <0 / >=512)

    // ---- Core staging: 18 rows x 128 float4, aligned & coalesced ----
#pragma unroll
    for (int i = 0; i < 9; ++i) {
        const int idx = tid + i * 256;       // 0..2303
        const int r = idx >> 7;              // row 0..17
        const int c4 = (idx & 127) << 2;     // col 0,4,..,508
        int gr = rbase + r;                  // row reflect (per-row cost only)
        gr = (gr < 0) ? (-gr - 1) : gr;
        gr = (gr >= IN_H) ? (2 * IN_H - 1 - gr) : gr;
        const float4 v = *(const float4*)&xp[gr * IN_W + c4];
        *(float4*)&tile[r][4 + c4] = v;      // 16B-aligned LDS store
    }

    // ---- Edge cols: tile cols {0,1}=0, {2,3}<-x[.,1],x[.,0], {516..519}<-x[.,511..508]
    if (tid < 8 * NROWS) {                   // 144 threads
        const int r = tid >> 3;
        const int e = tid & 7;
        const int tcol = (e < 4) ? e : (512 + e);        // 0,1,2,3,516..519
        float v = 0.0f;
        if (e >= 2) {
            const int scol = (e < 4) ? (3 - e) : (515 - e);  // 1,0,511..508
            int gr = rbase + r;
            gr = (gr < 0) ? (-gr - 1) : gr;
            gr = (gr >= IN_H) ? (2 * IN_H - 1 - gr) : gr;
            v = xp[gr * IN_W + scol];
        }
        tile[r][tcol] = v;
    }
    __syncthreads();

    // db2 dec_lo reversed
    const float g0 = 0.48296291314469025f;
    const float g1 = 0.8365163037378079f;
    const float g2 = 0.22414386804185735f;
    const float g3 = -0.12940952255092145f;

    // ---- Compute: thread -> output column(s); tile col = gc + 4 ----
    for (int ow = tid; ow < OUT_W; ow += 256) {
        const int cc = 2 * ow + 2;           // gc = 2*ow-2 .. 2*ow+1
        float h[NROWS];
#pragma unroll
        for (int r = 0; r < NROWS; ++r) {
            const float2 a = *(const float2*)&tile[r][cc];
            const float2 b = *(const float2*)&tile[r][cc + 2];
            h[r] = g0 * a.x + g1 * a.y + g2 * b.x + g3 * b.y;
        }
#pragma unroll
        for (int k = 0; k < TH; ++k) {
            const int oh = TH * by + k;
            if (oh < OUT_H) {
                op[oh * OUT_W + ow] = g0 * h[2 * k] + g1 * h[2 * k + 1]
                                    + g2 * h[2 * k + 2] + g3 * h[2 * k + 3];
            }
        }
    }
}

extern "C" void kernel_launch(void* const* d_in, const int* in_sizes, int n_in,
                              void* d_out, int out_size, void* d_ws, size_t ws_size,
                              hipStream_t stream) {
    const float* x = (const float*)d_in[0];
    float* out = (float*)d_out;

    dim3 grid((OUT_H + TH - 1) / TH, 4 * 64);  // 33 row-slabs x 256 planes
    dim3 block(256);
    dwt_ll_kernel<<<grid, block, 0, stream>>>(x, out);
}